// Round 6
// baseline (2551.280 us; speedup 1.0000x reference)
//
#include <hip/hip_runtime.h>

// 2-layer LSTM encoder, fused, v6: K-slice partial-dot + LDS reduction.
//
// ROUND-5 FINDING: v5 was LDS-PIPE-BOUND: every gate-lane broadcast-read the
// full h vector (152 DS inst/step/CU ~= 1600 cyc ~= measured 1440). Fix:
// each wave reads a DISJOINT K-slice exactly once (24 b128 floor), computes
// partials for ALL gates over its slice, and a single wave reduces partials.
//
// 64 blocks (one per batch elem), 256 threads = 4 waves, 1 wave/SIMD
// (amdgpu_waves_per_eu(1,1) -> 512-VGPR budget, weights stay resident).
//
// Phase A (all waves w=0..3): read h1[16w:16w+16) (4 ds_read_b128) and
//   h2[8w:8w+8) (2 b128). Lane u: partial dots for l1 unit u, 4 types
//   (4x16 FMA). Lane (p=lane>>5, v=lane&31): l2 unit v types {2p,2p+1}
//   (2x24 FMA). Wave 2 adds bias1 + W_ih1*x (x register-prefetched,
//   broadcast global load). Wave 0 adds bias2. Partials -> q1/q2 LDS rows
//   (stride QS=18 dwords: 16B-align-free, <=4-way b64 conflicts).
// Phase B: wave 0 reduces q1 row u (8 b64), activates, c1, writes h1s[u].
//   wave 1 (lanes<32) reduces q2 row v, c2, writes h2s[v] + out.
// Pipeline (as v5): iter n = l1 step n + l2 step n-1; both use h1(n-1).
// Single-buffer h1s/h2s/q*: reads and writes are barrier-separated phases.

#define BATCH 64
#define T 4096
#define H1 64
#define H2 32
#define NTHREADS 256
#define QS 18                      // q-row stride (dwords); padded vs 16
#define L2E 1.442695040888963f

__device__ __forceinline__ float fast_rcp(float v){ return __builtin_amdgcn_rcpf(v); }
__device__ __forceinline__ float sigm(float s){ return fast_rcp(1.0f + exp2f(-L2E*s)); }
__device__ __forceinline__ float tanh_(float s){ return 1.0f - 2.0f*fast_rcp(exp2f(2.0f*L2E*s) + 1.0f); }

#define DOT4(acc, W, H) acc = fmaf((H).x,(W).x, fmaf((H).y,(W).y, fmaf((H).z,(W).z, fmaf((H).w,(W).w, acc))))

__global__ __launch_bounds__(NTHREADS)
__attribute__((amdgpu_waves_per_eu(1, 1)))
void lstm2_fused_v6(const float* __restrict__ x,
                    const float* __restrict__ W_ih1, const float* __restrict__ W_hh1,
                    const float* __restrict__ b_ih1, const float* __restrict__ b_hh1,
                    const float* __restrict__ W_ih2, const float* __restrict__ W_hh2,
                    const float* __restrict__ b_ih2, const float* __restrict__ b_hh2,
                    float* __restrict__ out)
{
    const int b = blockIdx.x, tid = threadIdx.x;
    const int w = tid >> 6, lane = tid & 63;
    const int u = lane;                 // layer-1 unit owned in phase A/B
    const int v = lane & 31;            // layer-2 unit
    const int p = lane >> 5;            // layer-2 type-pair selector

    __shared__ __align__(16) float h1s[H1];
    __shared__ __align__(16) float h2s[H2];
    __shared__ __align__(16) float q1[H1 * QS];   // row u, cols 4w+t
    __shared__ __align__(16) float q2[H2 * QS];   // row v, cols 4w+t

    if (tid < H1)            h1s[tid] = 0.0f;
    else if (tid < H1 + H2)  h2s[tid - H1] = 0.0f;

    // ---- weights: per-wave K-slices, register-resident ----
    float4 w1[4][4];                    // W_hh1 rows 64t+u, cols [16w,16w+16)
    #pragma unroll
    for (int t = 0; t < 4; ++t){
        const float4* r = (const float4*)(W_hh1 + (size_t)(64*t + u)*H1 + 16*w);
        w1[t][0]=r[0]; w1[t][1]=r[1]; w1[t][2]=r[2]; w1[t][3]=r[3];
    }
    float4 w2i[2][4], w2h[2][2];        // W_ih2 / W_hh2 rows 32(2p+e)+v
    #pragma unroll
    for (int e = 0; e < 2; ++e){
        const int g2 = 32*(2*p + e) + v;
        const float4* ri = (const float4*)(W_ih2 + (size_t)g2*H1 + 16*w);
        w2i[e][0]=ri[0]; w2i[e][1]=ri[1]; w2i[e][2]=ri[2]; w2i[e][3]=ri[3];
        const float4* rh = (const float4*)(W_hh2 + (size_t)g2*H2 + 8*w);
        w2h[e][0]=rh[0]; w2h[e][1]=rh[1];
    }
    float4 w1x[4] = {}; float bias1[4] = {}; float bias2[2] = {};
    if (w == 2){                        // wave 2 carries bias1 + x-term
        #pragma unroll
        for (int t = 0; t < 4; ++t){
            w1x[t] = *(const float4*)(W_ih1 + (size_t)(64*t + u)*4);
            bias1[t] = b_ih1[64*t + u] + b_hh1[64*t + u];
        }
    }
    if (w == 0){                        // wave 0 carries bias2
        #pragma unroll
        for (int e = 0; e < 2; ++e){
            const int g2 = 32*(2*p + e) + v;
            bias2[e] = b_ih2[g2] + b_hh2[g2];
        }
    }

    const float4* xptr = (const float4*)(x + (size_t)b * T * 4);
    float4 xc = {};
    if (w == 2) xc = xptr[0];           // register prefetch of x[b,0,:]
    float* outb = out + (size_t)b * T * H2;

    float c1 = 0.0f, c2 = 0.0f;
    __syncthreads();

    for (int n = 0; n <= T; ++n){
        // ---------------- PHASE A: slice partial dots ----------------
        const float4* h1v = (const float4*)(h1s + 16*w);
        const float4* h2v = (const float4*)(h2s + 8*w);
        float4 ha0 = h1v[0], ha1 = h1v[1], ha2 = h1v[2], ha3 = h1v[3];
        float4 hb0 = h2v[0], hb1 = h2v[1];

        if (n < T){                     // layer-1 partials (step n)
            float P0, P1, P2, P3;
            if (w == 2){
                P0 = bias1[0]; DOT4(P0, w1x[0], xc);
                P1 = bias1[1]; DOT4(P1, w1x[1], xc);
                P2 = bias1[2]; DOT4(P2, w1x[2], xc);
                P3 = bias1[3]; DOT4(P3, w1x[3], xc);
                if (n + 1 < T) xc = xptr[n + 1];   // broadcast global prefetch
            } else { P0 = P1 = P2 = P3 = 0.0f; }
            DOT4(P0, w1[0][0], ha0); DOT4(P0, w1[0][1], ha1); DOT4(P0, w1[0][2], ha2); DOT4(P0, w1[0][3], ha3);
            DOT4(P1, w1[1][0], ha0); DOT4(P1, w1[1][1], ha1); DOT4(P1, w1[1][2], ha2); DOT4(P1, w1[1][3], ha3);
            DOT4(P2, w1[2][0], ha0); DOT4(P2, w1[2][1], ha1); DOT4(P2, w1[2][2], ha2); DOT4(P2, w1[2][3], ha3);
            DOT4(P3, w1[3][0], ha0); DOT4(P3, w1[3][1], ha1); DOT4(P3, w1[3][2], ha2); DOT4(P3, w1[3][3], ha3);
            *(float2*)&q1[QS*u + 4*w    ] = make_float2(P0, P1);
            *(float2*)&q1[QS*u + 4*w + 2] = make_float2(P2, P3);
        }
        {                               // layer-2 partials (output step n-1)
            float Q0 = (w == 0) ? bias2[0] : 0.0f;
            float Q1 = (w == 0) ? bias2[1] : 0.0f;
            DOT4(Q0, w2i[0][0], ha0); DOT4(Q0, w2i[0][1], ha1); DOT4(Q0, w2i[0][2], ha2); DOT4(Q0, w2i[0][3], ha3);
            DOT4(Q0, w2h[0][0], hb0); DOT4(Q0, w2h[0][1], hb1);
            DOT4(Q1, w2i[1][0], ha0); DOT4(Q1, w2i[1][1], ha1); DOT4(Q1, w2i[1][2], ha2); DOT4(Q1, w2i[1][3], ha3);
            DOT4(Q1, w2h[1][0], hb0); DOT4(Q1, w2h[1][1], hb1);
            *(float2*)&q2[QS*v + 4*w + 2*p] = make_float2(Q0, Q1);
        }
        __syncthreads();

        // ---------------- PHASE B: reduce + activate + state ----------------
        if (w == 0 && n < T){           // layer-1 finalize -> h1(n)
            float2 r0 = *(const float2*)&q1[QS*u +  0];
            float2 r1 = *(const float2*)&q1[QS*u +  2];
            float2 r2 = *(const float2*)&q1[QS*u +  4];
            float2 r3 = *(const float2*)&q1[QS*u +  6];
            float2 r4 = *(const float2*)&q1[QS*u +  8];
            float2 r5 = *(const float2*)&q1[QS*u + 10];
            float2 r6 = *(const float2*)&q1[QS*u + 12];
            float2 r7 = *(const float2*)&q1[QS*u + 14];
            float s0 = (r0.x + r2.x) + (r4.x + r6.x);
            float s1 = (r0.y + r2.y) + (r4.y + r6.y);
            float s2 = (r1.x + r3.x) + (r5.x + r7.x);
            float s3 = (r1.y + r3.y) + (r5.y + r7.y);
            float gi = sigm(s0), gf = sigm(s1), gg = tanh_(s2), go = sigm(s3);
            c1 = fmaf(gf, c1, gi * gg);
            h1s[u] = go * tanh_(c1);
        } else if (w == 1 && n >= 1 && lane < 32){   // layer-2 finalize -> h2(n-1), out
            float2 r0 = *(const float2*)&q2[QS*v +  0];
            float2 r1 = *(const float2*)&q2[QS*v +  2];
            float2 r2 = *(const float2*)&q2[QS*v +  4];
            float2 r3 = *(const float2*)&q2[QS*v +  6];
            float2 r4 = *(const float2*)&q2[QS*v +  8];
            float2 r5 = *(const float2*)&q2[QS*v + 10];
            float2 r6 = *(const float2*)&q2[QS*v + 12];
            float2 r7 = *(const float2*)&q2[QS*v + 14];
            float s0 = (r0.x + r2.x) + (r4.x + r6.x);
            float s1 = (r0.y + r2.y) + (r4.y + r6.y);
            float s2 = (r1.x + r3.x) + (r5.x + r7.x);
            float s3 = (r1.y + r3.y) + (r5.y + r7.y);
            float gi = sigm(s0), gf = sigm(s1), gg = tanh_(s2), go = sigm(s3);
            c2 = fmaf(gf, c2, gi * gg);
            float h = go * tanh_(c2);
            h2s[v] = h;
            outb[(size_t)(n - 1) * H2 + v] = h;
        }
        __syncthreads();
    }
}

extern "C" void kernel_launch(void* const* d_in, const int* in_sizes, int n_in,
                              void* d_out, int out_size, void* d_ws, size_t ws_size,
                              hipStream_t stream) {
    const float* x     = (const float*)d_in[0];
    const float* W_ih1 = (const float*)d_in[1];
    const float* W_hh1 = (const float*)d_in[2];
    const float* b_ih1 = (const float*)d_in[3];
    const float* b_hh1 = (const float*)d_in[4];
    const float* W_ih2 = (const float*)d_in[5];
    const float* W_hh2 = (const float*)d_in[6];
    const float* b_ih2 = (const float*)d_in[7];
    const float* b_hh2 = (const float*)d_in[8];
    float* out = (float*)d_out;

    lstm2_fused_v6<<<dim3(BATCH), dim3(NTHREADS), 0, stream>>>(
        x, W_ih1, W_hh1, b_ih1, b_hh1, W_ih2, W_hh2, b_ih2, b_hh2, out);
}